// Round 19
// baseline (715.181 us; speedup 1.0000x reference)
//
#include <hip/hip_runtime.h>

typedef __attribute__((ext_vector_type(4))) float f32x4;
typedef __attribute__((ext_vector_type(8))) short bf16x8;
typedef __attribute__((ext_vector_type(2))) unsigned int u32x2;

#define NHEAD 6

__device__ __forceinline__ unsigned short f2bf(float f){
  union{float f;unsigned int u;}c; c.f=f;
  unsigned int x=c.u;
  return (unsigned short)((x + 0x7FFFu + ((x>>16)&1u)) >> 16);
}
// packed f32x2 -> bf16x2 in ONE instruction (RNE)
__device__ __forceinline__ unsigned int cvtpk(float a, float b){
  unsigned int r;
  asm("v_cvt_pk_bf16_f32 %0, %1, %2" : "=v"(r) : "v"(a), "v"(b));
  return r;
}
__device__ __forceinline__ float bfl(unsigned int u){ union{unsigned int u;float f;}c; c.u=u<<16; return c.f; }
__device__ __forceinline__ float bfh(unsigned int u){ union{unsigned int u;float f;}c; c.u=u&0xFFFF0000u; return c.f; }

// ---------------- weight cast+transpose: wt[n*K+k] = bf16(w[k*N+n]) ----------------
__global__ void wt_kernel(const float* __restrict__ w, unsigned short* __restrict__ wt,
                          int K, int N){
  int idx = blockIdx.x*256 + threadIdx.x;
  if (idx >= K*N) return;
  int k = idx / N, n = idx - k*N;
  wt[(size_t)n*K + k] = f2bf(w[idx]);
}

// ---------------- LayerNorm1 + shift + window-partition, f32 in -> bf16 out ----------
__global__ __launch_bounds__(256) void ln_kernel(const float* __restrict__ x,
    const float* __restrict__ gw, const float* __restrict__ bw,
    unsigned short* __restrict__ out){
  int tok  = blockIdx.x*4 + (threadIdx.x>>6);
  int lane = threadIdx.x & 63;
  const float* row = x + (size_t)tok*192;
  float4 v = make_float4(0.f,0.f,0.f,0.f);
  if (lane < 48) v = *(const float4*)(row + lane*4);
  float s  = v.x+v.y+v.z+v.w;
  float s2 = v.x*v.x+v.y*v.y+v.z*v.z+v.w*v.w;
  #pragma unroll
  for (int off=32; off; off>>=1){ s += __shfl_xor(s,off); s2 += __shfl_xor(s2,off); }
  float mu = s*(1.f/192.f);
  float rs = rsqrtf(s2*(1.f/192.f) - mu*mu + 1e-5f);
  int b = tok/3136; int hw = tok - b*3136; int h = hw/56; int w = hw - h*56;
  int hs = h-3; if (hs<0) hs += 56;
  int wsh = w-3; if (wsh<0) wsh += 56;
  int wr = hs/7, r = hs - wr*7, wc = wsh/7, c = wsh - wc*7;
  size_t otok = ((size_t)b*64 + wr*8 + wc)*49 + r*7 + c;
  if (lane < 48){
    int cb = lane*4;
    float4 g4 = *(const float4*)(gw + cb);
    float4 b4 = *(const float4*)(bw + cb);
    u32x2 o;
    o.x = cvtpk((v.x-mu)*rs*g4.x + b4.x, (v.y-mu)*rs*g4.y + b4.y);
    o.y = cvtpk((v.z-mu)*rs*g4.z + b4.z, (v.w-mu)*rs*g4.w + b4.w);
    *(u32x2*)(out + otok*192 + cb) = o;
  }
}

// ---------------- LayerNorm2: bf16 in -> bf16 out (linear rows) ----------------------
__global__ __launch_bounds__(256) void ln_bf16_kernel(const unsigned short* __restrict__ xb,
    const float* __restrict__ gw, const float* __restrict__ bw,
    unsigned short* __restrict__ out){
  int tok  = blockIdx.x*4 + (threadIdx.x>>6);
  int lane = threadIdx.x & 63;
  const unsigned short* row = xb + (size_t)tok*192;
  float4 v = make_float4(0.f,0.f,0.f,0.f);
  if (lane < 48){
    u32x2 t = *(const u32x2*)(row + lane*4);
    v.x = bfl(t.x); v.y = bfh(t.x); v.z = bfl(t.y); v.w = bfh(t.y);
  }
  float s  = v.x+v.y+v.z+v.w;
  float s2 = v.x*v.x+v.y*v.y+v.z*v.z+v.w*v.w;
  #pragma unroll
  for (int off=32; off; off>>=1){ s += __shfl_xor(s,off); s2 += __shfl_xor(s2,off); }
  float mu = s*(1.f/192.f);
  float rs = rsqrtf(s2*(1.f/192.f) - mu*mu + 1e-5f);
  if (lane < 48){
    int cb = lane*4;
    float4 g4 = *(const float4*)(gw + cb);
    float4 b4 = *(const float4*)(bw + cb);
    u32x2 o;
    o.x = cvtpk((v.x-mu)*rs*g4.x + b4.x, (v.y-mu)*rs*g4.y + b4.y);
    o.y = cvtpk((v.z-mu)*rs*g4.z + b4.z, (v.w-mu)*rs*g4.w + b4.w);
    *(u32x2*)(out + (size_t)tok*192 + cb) = o;
  }
}

enum { EPI_QKV=0, EPI_PROJ=1, EPI_GELU=2, EPI_FINAL=3 };

// gelu(v) = v * sigmoid(v*(1.59576912 + 0.07135481 v^2))
__device__ __forceinline__ float gelu_fast(float v){
  float t = v*(1.59576912f + 0.07135481f*v*v);
  float e = __expf(-t);
  return v/(1.f + e);
}

__device__ __forceinline__ size_t proj_rowbase(int grow){
  int winr = grow/49; int nn = grow - winr*49;
  int b  = winr>>6; int wi = winr&63; int wr_ = wi>>3; int wc_ = wi&7;
  int r7 = nn/7;  int c7 = nn - r7*7;
  int h = wr_*7 + r7 + 3; if (h>=56) h-=56;
  int w = wc_*7 + c7 + 3; if (w>=56) w-=56;
  return (((size_t)b*3136) + h*56 + w)*192;
}

// ---------------- GEMM: 256x64 tile, BK=64, 8 waves (R18 form) ----------------------
template<int EPI>
__global__ __launch_bounds__(512) void gemm_k(
    const unsigned short* __restrict__ A,
    const unsigned short* __restrict__ BT,
    const float* __restrict__ bias,
    const float* __restrict__ res,
    void* __restrict__ Cout,
    int M, int N, int Nb, int K)
{
  __shared__ unsigned short lA[256*64];
  __shared__ unsigned short lB[64*64];
  const int tid  = threadIdx.x;
  const int wave = tid>>6, lane = tid&63;
  const int wm = wave>>1, wn = wave&1;
  const int lr = lane&15, lh = lane>>4;

  int bid = blockIdx.x;
  int yb = bid/(8*Nb); int rr = bid - yb*8*Nb; int xq = rr>>3; int y8 = rr&7;
  const int m0 = (yb*8 + y8)*256, n0 = xq*64;

  f32x4 zero = {0.f,0.f,0.f,0.f};
  f32x4 acc[4][2];
  #pragma unroll
  for (int i=0;i<4;i++){ acc[i][0]=zero; acc[i][1]=zero; }

  const int row8 = tid>>3;
  const int csw  = ((tid&7) ^ (row8&7))*8;
  const unsigned short* Ag = A  + (size_t)(m0 + row8)*K + csw;
  const unsigned short* Bg = BT + (size_t)(n0 + row8)*K + csw;

  for (int kt=0; kt<K; kt+=64){
    __syncthreads();
    #pragma unroll
    for (int i=0;i<4;i++){
      __builtin_amdgcn_global_load_lds(
        (const __attribute__((address_space(1))) void*)(Ag + (size_t)i*64*K + kt),
        (__attribute__((address_space(3))) void*)(lA + i*4096 + wave*512),
        16, 0, 0);
    }
    __builtin_amdgcn_global_load_lds(
      (const __attribute__((address_space(1))) void*)(Bg + kt),
      (__attribute__((address_space(3))) void*)(lB + wave*512),
      16, 0, 0);
    __syncthreads();

    bf16x8 af[4][2], bfv[2][2];
    #pragma unroll
    for (int mi=0;mi<4;mi++)
      #pragma unroll
      for (int ks=0;ks<2;ks++){
        int arow = wm*64+mi*16+lr;
        af[mi][ks] = *(const bf16x8*)&lA[arow*64 + (((ks*4+lh) ^ (lr&7))*8)];
      }
    #pragma unroll
    for (int ni=0;ni<2;ni++)
      #pragma unroll
      for (int ks=0;ks<2;ks++){
        int brow = wn*32+ni*16+lr;
        bfv[ni][ks] = *(const bf16x8*)&lB[brow*64 + (((ks*4+lh) ^ (lr&7))*8)];
      }
    #pragma unroll
    for (int mi=0;mi<4;mi++)
      #pragma unroll
      for (int ni=0;ni<2;ni++)
        #pragma unroll
        for (int ks=0;ks<2;ks++)
          acc[mi][ni] = __builtin_amdgcn_mfma_f32_16x16x32_bf16(
              bfv[ni][ks], af[mi][ks], acc[mi][ni], 0,0,0);
  }

  if (EPI == EPI_QKV || EPI == EPI_GELU || EPI == EPI_PROJ){
    __syncthreads();
    #pragma unroll
    for (int mi=0;mi<4;mi++){
      int row = wm*64 + mi*16 + lr;
      #pragma unroll
      for (int ni=0;ni<2;ni++){
        int colb = n0 + wn*32 + ni*16 + lh*4;
        float4 bv4 = *(const float4*)(bias + colb);
        float v0 = acc[mi][ni][0] + bv4.x;
        float v1 = acc[mi][ni][1] + bv4.y;
        float v2 = acc[mi][ni][2] + bv4.z;
        float v3 = acc[mi][ni][3] + bv4.w;
        u32x2 st;
        if (EPI == EPI_GELU){
          st.x = cvtpk(gelu_fast(v0), gelu_fast(v1));
          st.y = cvtpk(gelu_fast(v2), gelu_fast(v3));
        } else {
          st.x = cvtpk(v0,v1); st.y = cvtpk(v2,v3);
        }
        int c16 = wn*4 + ni*2 + (lh>>1);
        int byte = row*128 + ((c16 ^ (row&7))*16) + (lh&1)*8;
        *(u32x2*)((char*)lA + byte) = st;
      }
    }
    __syncthreads();
    #pragma unroll
    for (int rnd=0; rnd<4; ++rnd){
      int row = rnd*64 + (tid>>3);
      int chunk = tid&7;
      uint4 vv = *(const uint4*)((const char*)lA + row*128 + ((chunk ^ (row&7))*16));
      int grow = m0 + row;
      if (EPI == EPI_GELU){
        *(uint4*)((unsigned short*)Cout + (size_t)grow*N + n0 + chunk*8) = vv;
      } else if (EPI == EPI_QKV){
        int winr = grow/49; int nn = grow - winr*49;
        int gcol = n0 + chunk*8;
        int which = gcol/192; int rem = gcol - which*192;
        int head = rem>>5, d = rem&31;
        *(uint4*)((unsigned short*)Cout + (size_t)winr*28224 + (size_t)which*9408
                  + head*1568 + nn*32 + d) = vv;
      } else { // EPI_PROJ: x2 = x[prow] + proj (bf16 store)
        size_t base = proj_rowbase(grow) + n0 + chunk*8;
        float4 r0 = *(const float4*)(res + base);
        float4 r1 = *(const float4*)(res + base + 4);
        uint4 o;
        o.x = cvtpk(bfl(vv.x)+r0.x, bfh(vv.x)+r0.y);
        o.y = cvtpk(bfl(vv.y)+r0.z, bfh(vv.y)+r0.w);
        o.z = cvtpk(bfl(vv.z)+r1.x, bfh(vv.z)+r1.y);
        o.w = cvtpk(bfl(vv.w)+r1.z, bfh(vv.w)+r1.w);
        *(uint4*)((unsigned short*)Cout + base) = o;
      }
    }
  } else {
    // EPI_FINAL: f32 tile [128][64]; two halves; residual read as bf16
    float* Tf = (float*)lA;
    #pragma unroll
    for (int h=0; h<2; ++h){
      __syncthreads();
      if ((wave>>2) == h){
        #pragma unroll
        for (int mi=0;mi<4;mi++){
          int lrow = (wm&1)*64 + mi*16 + lr;
          #pragma unroll
          for (int ni=0;ni<2;ni++){
            int colb = n0 + wn*32 + ni*16 + lh*4;
            float4 bv4 = *(const float4*)(bias + colb);
            float4 val = make_float4(acc[mi][ni][0]+bv4.x, acc[mi][ni][1]+bv4.y,
                                     acc[mi][ni][2]+bv4.z, acc[mi][ni][3]+bv4.w);
            int c4 = wn*8 + ni*4 + lh;
            *(float4*)&Tf[lrow*64 + ((c4 ^ (lrow&15))*4)] = val;
          }
        }
      }
      __syncthreads();
      #pragma unroll
      for (int rnd=0; rnd<4; ++rnd){
        int lrow = rnd*32 + (tid>>4);
        int chunk = tid&15;
        float4 v = *(const float4*)&Tf[lrow*64 + ((chunk ^ (lrow&15))*4)];
        int grow = m0 + h*128 + lrow;
        size_t base = (size_t)grow*N + n0 + chunk*4;
        u32x2 rb = *(const u32x2*)((const unsigned short*)res + base);
        *(float4*)((float*)Cout + base) = make_float4(
            bfl(rb.x)+v.x, bfh(rb.x)+v.y, bfl(rb.y)+v.z, bfh(rb.y)+v.w);
      }
    }
  }
}

// ---------------- mlp1 GEMM: 256x128 tile, BK=64, 8 waves (4Mx2N), wave tile 64x64 --
// Halves A-panel cache re-fetch (6x vs 12x) and doubles MFMA per ds_read (32/16).
// Epilogue: GELU + bf16 through 32KB LDS tile in two 64-col halves.
__global__ __launch_bounds__(512) void gemm_gelu128(
    const unsigned short* __restrict__ A,
    const unsigned short* __restrict__ BT,
    const float* __restrict__ bias,
    unsigned short* __restrict__ Cout,
    int M, int N, int Nb, int K)
{
  __shared__ unsigned short lA[256*64];   // 32KB (reused as epilogue tile)
  __shared__ unsigned short lB[128*64];   // 16KB
  const int tid  = threadIdx.x;
  const int wave = tid>>6, lane = tid&63;
  const int wm = wave>>1, wn = wave&1;
  const int lr = lane&15, lh = lane>>4;

  int bid = blockIdx.x;
  int yb = bid/(8*Nb); int rr = bid - yb*8*Nb; int xq = rr>>3; int y8 = rr&7;
  const int m0 = (yb*8 + y8)*256, n0 = xq*128;

  f32x4 zero = {0.f,0.f,0.f,0.f};
  f32x4 acc[4][4];
  #pragma unroll
  for (int i=0;i<4;i++)
    #pragma unroll
    for (int j=0;j<4;j++) acc[i][j]=zero;

  const int row8 = tid>>3;
  const int csw  = ((tid&7) ^ (row8&7))*8;
  const unsigned short* Ag = A  + (size_t)(m0 + row8)*K + csw;
  const unsigned short* Bg = BT + (size_t)(n0 + row8)*K + csw;

  for (int kt=0; kt<K; kt+=64){
    __syncthreads();
    #pragma unroll
    for (int i=0;i<4;i++){
      __builtin_amdgcn_global_load_lds(
        (const __attribute__((address_space(1))) void*)(Ag + (size_t)i*64*K + kt),
        (__attribute__((address_space(3))) void*)(lA + i*4096 + wave*512),
        16, 0, 0);
    }
    #pragma unroll
    for (int i=0;i<2;i++){
      __builtin_amdgcn_global_load_lds(
        (const __attribute__((address_space(1))) void*)(Bg + (size_t)i*64*K + kt),
        (__attribute__((address_space(3))) void*)(lB + i*4096 + wave*512),
        16, 0, 0);
    }
    __syncthreads();

    bf16x8 af[4][2], bfv[4][2];
    #pragma unroll
    for (int mi=0;mi<4;mi++)
      #pragma unroll
      for (int ks=0;ks<2;ks++){
        int arow = wm*64+mi*16+lr;
        af[mi][ks] = *(const bf16x8*)&lA[arow*64 + (((ks*4+lh) ^ (lr&7))*8)];
      }
    #pragma unroll
    for (int ni=0;ni<4;ni++)
      #pragma unroll
      for (int ks=0;ks<2;ks++){
        int brow = wn*64+ni*16+lr;
        bfv[ni][ks] = *(const bf16x8*)&lB[brow*64 + (((ks*4+lh) ^ (lr&7))*8)];
      }
    // acc[mi][ni][r] = C[m0+wm*64+mi*16+lr][n0+wn*64+ni*16+lh*4+r]
    #pragma unroll
    for (int mi=0;mi<4;mi++)
      #pragma unroll
      for (int ni=0;ni<4;ni++)
        #pragma unroll
        for (int ks=0;ks<2;ks++)
          acc[mi][ni] = __builtin_amdgcn_mfma_f32_16x16x32_bf16(
              bfv[ni][ks], af[mi][ks], acc[mi][ni], 0,0,0);
  }

  // epilogue: two 64-col halves through the 32KB bf16 tile
  #pragma unroll
  for (int h=0; h<2; ++h){
    __syncthreads();
    if (wn == h){
      #pragma unroll
      for (int mi=0;mi<4;mi++){
        int row = wm*64 + mi*16 + lr;
        #pragma unroll
        for (int ni=0;ni<4;ni++){
          int colb = n0 + h*64 + ni*16 + lh*4;
          float4 bv4 = *(const float4*)(bias + colb);
          u32x2 st;
          st.x = cvtpk(gelu_fast(acc[mi][ni][0]+bv4.x), gelu_fast(acc[mi][ni][1]+bv4.y));
          st.y = cvtpk(gelu_fast(acc[mi][ni][2]+bv4.z), gelu_fast(acc[mi][ni][3]+bv4.w));
          int c16 = ni*2 + (lh>>1);
          int byte = row*128 + ((c16 ^ (row&7))*16) + (lh&1)*8;
          *(u32x2*)((char*)lA + byte) = st;
        }
      }
    }
    __syncthreads();
    #pragma unroll
    for (int rnd=0; rnd<4; ++rnd){
      int row = rnd*64 + (tid>>3);
      int chunk = tid&7;
      uint4 vv = *(const uint4*)((const char*)lA + row*128 + ((chunk ^ (row&7))*16));
      int grow = m0 + row;
      *(uint4*)(Cout + (size_t)grow*N + n0 + h*64 + chunk*8) = vv;
    }
  }
}

// ---------------- MFMA attention: one wave per (window, head) ----------------
__global__ __launch_bounds__(256) void attn_kernel(const unsigned short* __restrict__ qkv,
                                                   unsigned short* __restrict__ aout){
  __shared__ __align__(16) unsigned short ldsQK[4][4096];
  __shared__ __align__(16) unsigned short ldsV[4][2048];
  const int wave = threadIdx.x>>6, lane = threadIdx.x&63;
  const int lr = lane&15, lh = lane>>4;
  const int unit = blockIdx.x*4 + wave;
  const int win  = unit/NHEAD, head = unit - win*NHEAD;

  unsigned short* Q  = ldsQK[wave];
  unsigned short* Kl = ldsQK[wave] + 2048;
  unsigned short* P  = ldsQK[wave];
  unsigned short* Vt = ldsV[wave];

  const size_t wbase = (size_t)win*28224 + (size_t)head*1568;
  const unsigned short* gQ = qkv + wbase;
  const unsigned short* gK = qkv + wbase + 9408;
  const unsigned short* gV = qkv + wbase + 18816;

  {
    uint4 z = make_uint4(0,0,0,0);
    #pragma unroll
    for (int i=0;i<4;i++) *(uint4*)&Vt[(i*64+lane)*8] = z;
  }

  #pragma unroll
  for (int i=0;i<4;i++){
    int idx = i*64 + lane;
    if (idx < 196){
      int row = idx>>2, blk = idx&3;
      int sb = (blk ^ (row&3) ^ ((row>>2)&3));
      uint4 dq = *(const uint4*)(gQ + idx*8);
      *(uint4*)&Q[row*32 + sb*8] = dq;
      uint4 dk = *(const uint4*)(gK + idx*8);
      *(uint4*)&Kl[row*32 + sb*8] = dk;
    }
  }
  #pragma unroll
  for (int i=0;i<4;i++){
    int idx = i*64 + lane;
    if (idx < 196){
      int row = idx>>2, d0 = (idx&3)*8;
      uint4 dv = *(const uint4*)(gV + idx*8);
      unsigned int wds[4] = {dv.x, dv.y, dv.z, dv.w};
      int rb = row>>3, re = row&7;
      #pragma unroll
      for (int j=0;j<8;j++){
        unsigned short t = (unsigned short)(wds[j>>1] >> ((j&1)*16));
        Vt[(d0+j)*64 + ((rb ^ j)*8) + re] = t;
      }
    }
  }

  bf16x8 kf[4], qf[4];
  #pragma unroll
  for (int t=0;t<4;t++){
    int row = t*16 + lr;
    int off = row*32 + ((lh ^ (row&3) ^ ((row>>2)&3))*8);
    kf[t] = *(const bf16x8*)&Kl[off];
    qf[t] = *(const bf16x8*)&Q[off];
  }

  f32x4 zero = {0.f,0.f,0.f,0.f};
  f32x4 S[4][4];
  #pragma unroll
  for (int mi=0;mi<4;mi++)
    #pragma unroll
    for (int ni=0;ni<4;ni++)
      S[mi][ni] = __builtin_amdgcn_mfma_f32_16x16x32_bf16(kf[mi], qf[ni], zero, 0,0,0);

  const int wi = win & 63, wr = wi>>3, wc = wi&7;
  const bool hasmask = (wr==7) || (wc==7);
  const float scale = 0.17677669529663687f;

  #pragma unroll
  for (int ni=0;ni<4;ni++){
    int q = ni*16 + lr;
    int idq = 0;
    if (hasmask){
      int qr = q/7, qc = q - qr*7;
      int ih = (wr==7) ? ((qr>=4)?2:1) : 0;
      int iw = (wc==7) ? ((qc>=4)?2:1) : 0;
      idq = ih*3 + iw;
    }
    #pragma unroll
    for (int mi=0;mi<4;mi++){
      #pragma unroll
      for (int r=0;r<4;r++){
        int key = mi*16 + lh*4 + r;
        float s;
        if (key >= 49) s = -1e30f;
        else {
          float add = 0.f;
          if (hasmask){
            int kr = key/7, kc = key - kr*7;
            int ih = (wr==7) ? ((kr>=4)?2:1) : 0;
            int iw = (wc==7) ? ((kc>=4)?2:1) : 0;
            add = ((ih*3+iw) == idq) ? 0.f : -100.f;
          }
          s = S[mi][ni][r]*scale + add;
        }
        S[mi][ni][r] = s;
      }
    }
    float m = -1e30f;
    #pragma unroll
    for (int mi=0;mi<4;mi++)
      #pragma unroll
      for (int r=0;r<4;r++) m = fmaxf(m, S[mi][ni][r]);
    m = fmaxf(m, __shfl_xor(m, 16));
    m = fmaxf(m, __shfl_xor(m, 32));
    float sum = 0.f;
    #pragma unroll
    for (int mi=0;mi<4;mi++)
      #pragma unroll
      for (int r=0;r<4;r++){
        float p = __expf(S[mi][ni][r] - m);
        S[mi][ni][r] = p; sum += p;
      }
    sum += __shfl_xor(sum, 16);
    sum += __shfl_xor(sum, 32);
    float inv = 1.f/sum;
    #pragma unroll
    for (int mi=0;mi<4;mi++){
      int keyb = mi*16 + lh*4;
      int blk = keyb>>3, e0 = keyb&7;
      int addr = q*64 + ((blk ^ (q&7))*8) + e0;
      *(unsigned int*)&P[addr]   = cvtpk(S[mi][ni][0]*inv, S[mi][ni][1]*inv);
      *(unsigned int*)&P[addr+2] = cvtpk(S[mi][ni][2]*inv, S[mi][ni][3]*inv);
    }
  }

  bf16x8 vf[2][2];
  #pragma unroll
  for (int mt=0;mt<2;mt++)
    #pragma unroll
    for (int ks=0;ks<2;ks++){
      int row = mt*16 + lr;
      vf[mt][ks] = *(const bf16x8*)&Vt[row*64 + (((ks*4+lh) ^ (row&7))*8)];
    }
  f32x4 O[2][4];
  #pragma unroll
  for (int ni=0;ni<4;ni++){
    int q = ni*16 + lr;
    bf16x8 pf0 = *(const bf16x8*)&P[q*64 + (((0*4+lh) ^ (q&7))*8)];
    bf16x8 pf1 = *(const bf16x8*)&P[q*64 + (((1*4+lh) ^ (q&7))*8)];
    #pragma unroll
    for (int mt=0;mt<2;mt++){
      f32x4 t = __builtin_amdgcn_mfma_f32_16x16x32_bf16(vf[mt][0], pf0, zero, 0,0,0);
      O[mt][ni] = __builtin_amdgcn_mfma_f32_16x16x32_bf16(vf[mt][1], pf1, t, 0,0,0);
    }
  }

  #pragma unroll
  for (int ni=0;ni<4;ni++){
    int q = ni*16 + lr;
    if (q < 49){
      size_t ob = ((size_t)win*49 + q)*192 + head*32 + lh*4;
      #pragma unroll
      for (int mt=0;mt<2;mt++){
        u32x2 st;
        st.x = cvtpk(O[mt][ni][0], O[mt][ni][1]);
        st.y = cvtpk(O[mt][ni][2], O[mt][ni][3]);
        *(u32x2*)(aout + ob + mt*16) = st;
      }
    }
  }
}

// ---------------- launcher ----------------
extern "C" void kernel_launch(void* const* d_in, const int* in_sizes, int n_in,
                              void* d_out, int out_size, void* d_ws, size_t ws_size,
                              hipStream_t stream){
  (void)in_sizes; (void)n_in; (void)out_size; (void)ws_size;
  const float* x      = (const float*)d_in[0];
  const float* n1_g   = (const float*)d_in[1];
  const float* n1_b   = (const float*)d_in[2];
  const float* qkv_w  = (const float*)d_in[3];
  const float* qkv_b  = (const float*)d_in[4];
  const float* proj_w = (const float*)d_in[5];
  const float* proj_b = (const float*)d_in[6];
  const float* n2_g   = (const float*)d_in[7];
  const float* n2_b   = (const float*)d_in[8];
  const float* w1     = (const float*)d_in[9];
  const float* b1     = (const float*)d_in[10];
  const float* w2     = (const float*)d_in[11];
  const float* b2     = (const float*)d_in[12];

  char* ws = (char*)d_ws;
  unsigned short* qkvT = (unsigned short*)(ws + 0);          // 576*192 bf16
  unsigned short* projT= (unsigned short*)(ws + 221184);     // 192*192
  unsigned short* w1T  = (unsigned short*)(ws + 294912);     // 768*192
  unsigned short* w2T  = (unsigned short*)(ws + 589824);     // 192*768
  unsigned short* bufA = (unsigned short*)(ws + 884736);     // 200704*192 bf16 (xw / attn-out / x2n)
  unsigned short* bufB = (unsigned short*)(ws + 77955072);   // 200704*768 bf16 (qkv / h)
  unsigned short* x2b  = (unsigned short*)(ws + 386236416);  // 200704*192 bf16 (x2)
  float* out = (float*)d_out;
  const int M = 200704;

  wt_kernel<<<432,256,0,stream>>>(qkv_w, qkvT, 192, 576);
  wt_kernel<<<144,256,0,stream>>>(proj_w, projT, 192, 192);
  wt_kernel<<<576,256,0,stream>>>(w1,    w1T,  192, 768);
  wt_kernel<<<576,256,0,stream>>>(w2,    w2T,  768, 192);

  ln_kernel<<<50176,256,0,stream>>>(x, n1_g, n1_b, bufA);
  gemm_k<EPI_QKV  ><<< 9*784, 512,0,stream>>>(bufA, qkvT, qkv_b, nullptr, bufB, M, 576, 9, 192);
  attn_kernel<<<6144,256,0,stream>>>(bufB, bufA);
  gemm_k<EPI_PROJ ><<< 3*784, 512,0,stream>>>(bufA, projT, proj_b, x, x2b, M, 192, 3, 192);
  ln_bf16_kernel<<<50176,256,0,stream>>>(x2b, n2_g, n2_b, bufA);
  gemm_gelu128<<< 6*784, 512,0,stream>>>(bufA, w1T, b1, bufB, M, 768, 6, 192);
  gemm_k<EPI_FINAL><<< 3*784, 512,0,stream>>>(bufB, w2T, b2, (const float*)x2b, out, M, 192, 3, 768);
}

// Round 20
// 666.177 us; speedup vs baseline: 1.0736x; 1.0736x over previous
//
#include <hip/hip_runtime.h>

typedef __attribute__((ext_vector_type(4))) float f32x4;
typedef __attribute__((ext_vector_type(8))) short bf16x8;
typedef __attribute__((ext_vector_type(2))) unsigned int u32x2;

#define NHEAD 6

__device__ __forceinline__ unsigned short f2bf(float f){
  union{float f;unsigned int u;}c; c.f=f;
  unsigned int x=c.u;
  return (unsigned short)((x + 0x7FFFu + ((x>>16)&1u)) >> 16);
}
// packed f32x2 -> bf16x2 in ONE instruction (RNE)
__device__ __forceinline__ unsigned int cvtpk(float a, float b){
  unsigned int r;
  asm("v_cvt_pk_bf16_f32 %0, %1, %2" : "=v"(r) : "v"(a), "v"(b));
  return r;
}
__device__ __forceinline__ float bfl(unsigned int u){ union{unsigned int u;float f;}c; c.u=u<<16; return c.f; }
__device__ __forceinline__ float bfh(unsigned int u){ union{unsigned int u;float f;}c; c.u=u&0xFFFF0000u; return c.f; }

// ---------------- weight cast+transpose: wt[n*K+k] = bf16(w[k*N+n]) ----------------
__global__ void wt_kernel(const float* __restrict__ w, unsigned short* __restrict__ wt,
                          int K, int N){
  int idx = blockIdx.x*256 + threadIdx.x;
  if (idx >= K*N) return;
  int k = idx / N, n = idx - k*N;
  wt[(size_t)n*K + k] = f2bf(w[idx]);
}

// ---------------- LayerNorm1 + shift + window-partition, f32 in -> bf16 out ----------
__global__ __launch_bounds__(256) void ln_kernel(const float* __restrict__ x,
    const float* __restrict__ gw, const float* __restrict__ bw,
    unsigned short* __restrict__ out){
  int tok  = blockIdx.x*4 + (threadIdx.x>>6);
  int lane = threadIdx.x & 63;
  const float* row = x + (size_t)tok*192;
  float4 v = make_float4(0.f,0.f,0.f,0.f);
  if (lane < 48) v = *(const float4*)(row + lane*4);
  float s  = v.x+v.y+v.z+v.w;
  float s2 = v.x*v.x+v.y*v.y+v.z*v.z+v.w*v.w;
  #pragma unroll
  for (int off=32; off; off>>=1){ s += __shfl_xor(s,off); s2 += __shfl_xor(s2,off); }
  float mu = s*(1.f/192.f);
  float rs = rsqrtf(s2*(1.f/192.f) - mu*mu + 1e-5f);
  int b = tok/3136; int hw = tok - b*3136; int h = hw/56; int w = hw - h*56;
  int hs = h-3; if (hs<0) hs += 56;
  int wsh = w-3; if (wsh<0) wsh += 56;
  int wr = hs/7, r = hs - wr*7, wc = wsh/7, c = wsh - wc*7;
  size_t otok = ((size_t)b*64 + wr*8 + wc)*49 + r*7 + c;
  if (lane < 48){
    int cb = lane*4;
    float4 g4 = *(const float4*)(gw + cb);
    float4 b4 = *(const float4*)(bw + cb);
    u32x2 o;
    o.x = cvtpk((v.x-mu)*rs*g4.x + b4.x, (v.y-mu)*rs*g4.y + b4.y);
    o.y = cvtpk((v.z-mu)*rs*g4.z + b4.z, (v.w-mu)*rs*g4.w + b4.w);
    *(u32x2*)(out + otok*192 + cb) = o;
  }
}

// ---------------- LayerNorm2: bf16 in -> bf16 out (linear rows) ----------------------
__global__ __launch_bounds__(256) void ln_bf16_kernel(const unsigned short* __restrict__ xb,
    const float* __restrict__ gw, const float* __restrict__ bw,
    unsigned short* __restrict__ out){
  int tok  = blockIdx.x*4 + (threadIdx.x>>6);
  int lane = threadIdx.x & 63;
  const unsigned short* row = xb + (size_t)tok*192;
  float4 v = make_float4(0.f,0.f,0.f,0.f);
  if (lane < 48){
    u32x2 t = *(const u32x2*)(row + lane*4);
    v.x = bfl(t.x); v.y = bfh(t.x); v.z = bfl(t.y); v.w = bfh(t.y);
  }
  float s  = v.x+v.y+v.z+v.w;
  float s2 = v.x*v.x+v.y*v.y+v.z*v.z+v.w*v.w;
  #pragma unroll
  for (int off=32; off; off>>=1){ s += __shfl_xor(s,off); s2 += __shfl_xor(s2,off); }
  float mu = s*(1.f/192.f);
  float rs = rsqrtf(s2*(1.f/192.f) - mu*mu + 1e-5f);
  if (lane < 48){
    int cb = lane*4;
    float4 g4 = *(const float4*)(gw + cb);
    float4 b4 = *(const float4*)(bw + cb);
    u32x2 o;
    o.x = cvtpk((v.x-mu)*rs*g4.x + b4.x, (v.y-mu)*rs*g4.y + b4.y);
    o.y = cvtpk((v.z-mu)*rs*g4.z + b4.z, (v.w-mu)*rs*g4.w + b4.w);
    *(u32x2*)(out + (size_t)tok*192 + cb) = o;
  }
}

enum { EPI_QKV=0, EPI_PROJ=1, EPI_GELU=2, EPI_FINAL=3 };

// gelu(v) = v * sigmoid(v*(1.59576912 + 0.07135481 v^2))
__device__ __forceinline__ float gelu_fast(float v){
  float t = v*(1.59576912f + 0.07135481f*v*v);
  float e = __expf(-t);
  return v/(1.f + e);
}

__device__ __forceinline__ size_t proj_rowbase(int grow){
  int winr = grow/49; int nn = grow - winr*49;
  int b  = winr>>6; int wi = winr&63; int wr_ = wi>>3; int wc_ = wi&7;
  int r7 = nn/7;  int c7 = nn - r7*7;
  int h = wr_*7 + r7 + 3; if (h>=56) h-=56;
  int w = wc_*7 + c7 + 3; if (w>=56) w-=56;
  return (((size_t)b*3136) + h*56 + w)*192;
}

// ---------------- GEMM: 256x64 tile, BK=64, 8 waves (R8 K-loop, R10 epilogues) ------
// EPI_QKV/EPI_GELU/EPI_PROJ: bf16 out via 32KB LDS-transposed tile (PROJ adds f32
// residual in the coalesced store phase, writes x2 as bf16).
// EPI_FINAL: f32 out via LDS-transposed f32 tile, residual read as bf16.
template<int EPI>
__global__ __launch_bounds__(512) void gemm_k(
    const unsigned short* __restrict__ A,
    const unsigned short* __restrict__ BT,
    const float* __restrict__ bias,
    const float* __restrict__ res,
    void* __restrict__ Cout,
    int M, int N, int Nb, int K)
{
  __shared__ unsigned short lA[256*64];
  __shared__ unsigned short lB[64*64];
  const int tid  = threadIdx.x;
  const int wave = tid>>6, lane = tid&63;
  const int wm = wave>>1, wn = wave&1;     // 4 x 2 wave grid
  const int lr = lane&15, lh = lane>>4;

  // XCD remap: bid = y8 + 8*(xq + Nb*yb)
  int bid = blockIdx.x;
  int yb = bid/(8*Nb); int rr = bid - yb*8*Nb; int xq = rr>>3; int y8 = rr&7;
  const int m0 = (yb*8 + y8)*256, n0 = xq*64;

  f32x4 zero = {0.f,0.f,0.f,0.f};
  f32x4 acc[4][2];
  #pragma unroll
  for (int i=0;i<4;i++){ acc[i][0]=zero; acc[i][1]=zero; }

  const int row8 = tid>>3;
  const int csw  = ((tid&7) ^ (row8&7))*8;
  const unsigned short* Ag = A  + (size_t)(m0 + row8)*K + csw;
  const unsigned short* Bg = BT + (size_t)(n0 + row8)*K + csw;

  for (int kt=0; kt<K; kt+=64){
    __syncthreads();
    #pragma unroll
    for (int i=0;i<4;i++){
      __builtin_amdgcn_global_load_lds(
        (const __attribute__((address_space(1))) void*)(Ag + (size_t)i*64*K + kt),
        (__attribute__((address_space(3))) void*)(lA + i*4096 + wave*512),
        16, 0, 0);
    }
    __builtin_amdgcn_global_load_lds(
      (const __attribute__((address_space(1))) void*)(Bg + kt),
      (__attribute__((address_space(3))) void*)(lB + wave*512),
      16, 0, 0);
    __syncthreads();

    bf16x8 af[4][2], bfv[2][2];
    #pragma unroll
    for (int mi=0;mi<4;mi++)
      #pragma unroll
      for (int ks=0;ks<2;ks++){
        int arow = wm*64+mi*16+lr;
        af[mi][ks] = *(const bf16x8*)&lA[arow*64 + (((ks*4+lh) ^ (lr&7))*8)];
      }
    #pragma unroll
    for (int ni=0;ni<2;ni++)
      #pragma unroll
      for (int ks=0;ks<2;ks++){
        int brow = wn*32+ni*16+lr;
        bfv[ni][ks] = *(const bf16x8*)&lB[brow*64 + (((ks*4+lh) ^ (lr&7))*8)];
      }
    #pragma unroll
    for (int mi=0;mi<4;mi++)
      #pragma unroll
      for (int ni=0;ni<2;ni++)
        #pragma unroll
        for (int ks=0;ks<2;ks++)
          acc[mi][ni] = __builtin_amdgcn_mfma_f32_16x16x32_bf16(
              bfv[ni][ks], af[mi][ks], acc[mi][ni], 0,0,0);
  }

  // ================= LDS-transposed epilogue =================
  if (EPI == EPI_QKV || EPI == EPI_GELU || EPI == EPI_PROJ){
    // bf16 tile [256 rows][64 cols] = 32KB in lA; 16B-chunk XOR swizzle (^ row&7)
    __syncthreads();
    #pragma unroll
    for (int mi=0;mi<4;mi++){
      int row = wm*64 + mi*16 + lr;
      #pragma unroll
      for (int ni=0;ni<2;ni++){
        int colb = n0 + wn*32 + ni*16 + lh*4;
        float4 bv4 = *(const float4*)(bias + colb);
        float v0 = acc[mi][ni][0] + bv4.x;
        float v1 = acc[mi][ni][1] + bv4.y;
        float v2 = acc[mi][ni][2] + bv4.z;
        float v3 = acc[mi][ni][3] + bv4.w;
        u32x2 st;
        if (EPI == EPI_GELU){
          st.x = cvtpk(gelu_fast(v0), gelu_fast(v1));
          st.y = cvtpk(gelu_fast(v2), gelu_fast(v3));
        } else {
          st.x = cvtpk(v0,v1); st.y = cvtpk(v2,v3);
        }
        int c16 = wn*4 + ni*2 + (lh>>1);
        int byte = row*128 + ((c16 ^ (row&7))*16) + (lh&1)*8;
        *(u32x2*)((char*)lA + byte) = st;
      }
    }
    __syncthreads();
    #pragma unroll
    for (int rnd=0; rnd<4; ++rnd){
      int row = rnd*64 + (tid>>3);          // 64 rows/round, 8 threads/row
      int chunk = tid&7;                     // 16B = 8 bf16 cols
      uint4 vv = *(const uint4*)((const char*)lA + row*128 + ((chunk ^ (row&7))*16));
      int grow = m0 + row;
      if (EPI == EPI_GELU){
        *(uint4*)((unsigned short*)Cout + (size_t)grow*N + n0 + chunk*8) = vv;
      } else if (EPI == EPI_QKV){
        int winr = grow/49; int nn = grow - winr*49;
        int gcol = n0 + chunk*8;
        int which = gcol/192; int rem = gcol - which*192;
        int head = rem>>5, d = rem&31;
        *(uint4*)((unsigned short*)Cout + (size_t)winr*28224 + (size_t)which*9408
                  + head*1568 + nn*32 + d) = vv;
      } else { // EPI_PROJ: x2 = x[prow] + proj (bf16 store)
        size_t base = proj_rowbase(grow) + n0 + chunk*8;
        float4 r0 = *(const float4*)(res + base);
        float4 r1 = *(const float4*)(res + base + 4);
        uint4 o;
        o.x = cvtpk(bfl(vv.x)+r0.x, bfh(vv.x)+r0.y);
        o.y = cvtpk(bfl(vv.y)+r0.z, bfh(vv.y)+r0.w);
        o.z = cvtpk(bfl(vv.z)+r1.x, bfh(vv.z)+r1.y);
        o.w = cvtpk(bfl(vv.w)+r1.z, bfh(vv.w)+r1.w);
        *(uint4*)((unsigned short*)Cout + base) = o;
      }
    }
  } else {
    // EPI_FINAL: f32 tile [128][64]; two halves; residual read as bf16
    float* Tf = (float*)lA;
    #pragma unroll
    for (int h=0; h<2; ++h){
      __syncthreads();
      if ((wave>>2) == h){
        #pragma unroll
        for (int mi=0;mi<4;mi++){
          int lrow = (wm&1)*64 + mi*16 + lr;
          #pragma unroll
          for (int ni=0;ni<2;ni++){
            int colb = n0 + wn*32 + ni*16 + lh*4;
            float4 bv4 = *(const float4*)(bias + colb);
            float4 val = make_float4(acc[mi][ni][0]+bv4.x, acc[mi][ni][1]+bv4.y,
                                     acc[mi][ni][2]+bv4.z, acc[mi][ni][3]+bv4.w);
            int c4 = wn*8 + ni*4 + lh;
            *(float4*)&Tf[lrow*64 + ((c4 ^ (lrow&15))*4)] = val;
          }
        }
      }
      __syncthreads();
      #pragma unroll
      for (int rnd=0; rnd<4; ++rnd){
        int lrow = rnd*32 + (tid>>4);
        int chunk = tid&15;                  // 16B = 4 f32 cols
        float4 v = *(const float4*)&Tf[lrow*64 + ((chunk ^ (lrow&15))*4)];
        int grow = m0 + h*128 + lrow;
        size_t base = (size_t)grow*N + n0 + chunk*4;
        u32x2 rb = *(const u32x2*)((const unsigned short*)res + base);
        *(float4*)((float*)Cout + base) = make_float4(
            bfl(rb.x)+v.x, bfh(rb.x)+v.y, bfl(rb.y)+v.z, bfh(rb.y)+v.w);
      }
    }
  }
}

// ---------------- MFMA attention: one wave per (window, head) ----------------
__global__ __launch_bounds__(256) void attn_kernel(const unsigned short* __restrict__ qkv,
                                                   unsigned short* __restrict__ aout){
  __shared__ __align__(16) unsigned short ldsQK[4][4096];
  __shared__ __align__(16) unsigned short ldsV[4][2048];
  const int wave = threadIdx.x>>6, lane = threadIdx.x&63;
  const int lr = lane&15, lh = lane>>4;
  const int unit = blockIdx.x*4 + wave;
  const int win  = unit/NHEAD, head = unit - win*NHEAD;

  unsigned short* Q  = ldsQK[wave];
  unsigned short* Kl = ldsQK[wave] + 2048;
  unsigned short* P  = ldsQK[wave];
  unsigned short* Vt = ldsV[wave];

  const size_t wbase = (size_t)win*28224 + (size_t)head*1568;
  const unsigned short* gQ = qkv + wbase;
  const unsigned short* gK = qkv + wbase + 9408;
  const unsigned short* gV = qkv + wbase + 18816;

  {
    uint4 z = make_uint4(0,0,0,0);
    #pragma unroll
    for (int i=0;i<4;i++) *(uint4*)&Vt[(i*64+lane)*8] = z;
  }

  #pragma unroll
  for (int i=0;i<4;i++){
    int idx = i*64 + lane;
    if (idx < 196){
      int row = idx>>2, blk = idx&3;
      int sb = (blk ^ (row&3) ^ ((row>>2)&3));
      uint4 dq = *(const uint4*)(gQ + idx*8);
      *(uint4*)&Q[row*32 + sb*8] = dq;
      uint4 dk = *(const uint4*)(gK + idx*8);
      *(uint4*)&Kl[row*32 + sb*8] = dk;
    }
  }
  #pragma unroll
  for (int i=0;i<4;i++){
    int idx = i*64 + lane;
    if (idx < 196){
      int row = idx>>2, d0 = (idx&3)*8;
      uint4 dv = *(const uint4*)(gV + idx*8);
      unsigned int wds[4] = {dv.x, dv.y, dv.z, dv.w};
      int rb = row>>3, re = row&7;
      #pragma unroll
      for (int j=0;j<8;j++){
        unsigned short t = (unsigned short)(wds[j>>1] >> ((j&1)*16));
        Vt[(d0+j)*64 + ((rb ^ j)*8) + re] = t;
      }
    }
  }

  bf16x8 kf[4], qf[4];
  #pragma unroll
  for (int t=0;t<4;t++){
    int row = t*16 + lr;
    int off = row*32 + ((lh ^ (row&3) ^ ((row>>2)&3))*8);
    kf[t] = *(const bf16x8*)&Kl[off];
    qf[t] = *(const bf16x8*)&Q[off];
  }

  f32x4 zero = {0.f,0.f,0.f,0.f};
  f32x4 S[4][4];
  #pragma unroll
  for (int mi=0;mi<4;mi++)
    #pragma unroll
    for (int ni=0;ni<4;ni++)
      S[mi][ni] = __builtin_amdgcn_mfma_f32_16x16x32_bf16(kf[mi], qf[ni], zero, 0,0,0);

  const int wi = win & 63, wr = wi>>3, wc = wi&7;
  const bool hasmask = (wr==7) || (wc==7);
  const float scale = 0.17677669529663687f;

  #pragma unroll
  for (int ni=0;ni<4;ni++){
    int q = ni*16 + lr;
    int idq = 0;
    if (hasmask){
      int qr = q/7, qc = q - qr*7;
      int ih = (wr==7) ? ((qr>=4)?2:1) : 0;
      int iw = (wc==7) ? ((qc>=4)?2:1) : 0;
      idq = ih*3 + iw;
    }
    #pragma unroll
    for (int mi=0;mi<4;mi++){
      #pragma unroll
      for (int r=0;r<4;r++){
        int key = mi*16 + lh*4 + r;
        float s;
        if (key >= 49) s = -1e30f;
        else {
          float add = 0.f;
          if (hasmask){
            int kr = key/7, kc = key - kr*7;
            int ih = (wr==7) ? ((kr>=4)?2:1) : 0;
            int iw = (wc==7) ? ((kc>=4)?2:1) : 0;
            add = ((ih*3+iw) == idq) ? 0.f : -100.f;
          }
          s = S[mi][ni][r]*scale + add;
        }
        S[mi][ni][r] = s;
      }
    }
    float m = -1e30f;
    #pragma unroll
    for (int mi=0;mi<4;mi++)
      #pragma unroll
      for (int r=0;r<4;r++) m = fmaxf(m, S[mi][ni][r]);
    m = fmaxf(m, __shfl_xor(m, 16));
    m = fmaxf(m, __shfl_xor(m, 32));
    float sum = 0.f;
    #pragma unroll
    for (int mi=0;mi<4;mi++)
      #pragma unroll
      for (int r=0;r<4;r++){
        float p = __expf(S[mi][ni][r] - m);
        S[mi][ni][r] = p; sum += p;
      }
    sum += __shfl_xor(sum, 16);
    sum += __shfl_xor(sum, 32);
    float inv = 1.f/sum;
    #pragma unroll
    for (int mi=0;mi<4;mi++){
      int keyb = mi*16 + lh*4;
      int blk = keyb>>3, e0 = keyb&7;
      int addr = q*64 + ((blk ^ (q&7))*8) + e0;
      *(unsigned int*)&P[addr]   = cvtpk(S[mi][ni][0]*inv, S[mi][ni][1]*inv);
      *(unsigned int*)&P[addr+2] = cvtpk(S[mi][ni][2]*inv, S[mi][ni][3]*inv);
    }
  }

  bf16x8 vf[2][2];
  #pragma unroll
  for (int mt=0;mt<2;mt++)
    #pragma unroll
    for (int ks=0;ks<2;ks++){
      int row = mt*16 + lr;
      vf[mt][ks] = *(const bf16x8*)&Vt[row*64 + (((ks*4+lh) ^ (row&7))*8)];
    }
  f32x4 O[2][4];
  #pragma unroll
  for (int ni=0;ni<4;ni++){
    int q = ni*16 + lr;
    bf16x8 pf0 = *(const bf16x8*)&P[q*64 + (((0*4+lh) ^ (q&7))*8)];
    bf16x8 pf1 = *(const bf16x8*)&P[q*64 + (((1*4+lh) ^ (q&7))*8)];
    #pragma unroll
    for (int mt=0;mt<2;mt++){
      f32x4 t = __builtin_amdgcn_mfma_f32_16x16x32_bf16(vf[mt][0], pf0, zero, 0,0,0);
      O[mt][ni] = __builtin_amdgcn_mfma_f32_16x16x32_bf16(vf[mt][1], pf1, t, 0,0,0);
    }
  }

  #pragma unroll
  for (int ni=0;ni<4;ni++){
    int q = ni*16 + lr;
    if (q < 49){
      size_t ob = ((size_t)win*49 + q)*192 + head*32 + lh*4;
      #pragma unroll
      for (int mt=0;mt<2;mt++){
        u32x2 st;
        st.x = cvtpk(O[mt][ni][0], O[mt][ni][1]);
        st.y = cvtpk(O[mt][ni][2], O[mt][ni][3]);
        *(u32x2*)(aout + ob + mt*16) = st;
      }
    }
  }
}

// ---------------- launcher ----------------
extern "C" void kernel_launch(void* const* d_in, const int* in_sizes, int n_in,
                              void* d_out, int out_size, void* d_ws, size_t ws_size,
                              hipStream_t stream){
  (void)in_sizes; (void)n_in; (void)out_size; (void)ws_size;
  const float* x      = (const float*)d_in[0];
  const float* n1_g   = (const float*)d_in[1];
  const float* n1_b   = (const float*)d_in[2];
  const float* qkv_w  = (const float*)d_in[3];
  const float* qkv_b  = (const float*)d_in[4];
  const float* proj_w = (const float*)d_in[5];
  const float* proj_b = (const float*)d_in[6];
  const float* n2_g   = (const float*)d_in[7];
  const float* n2_b   = (const float*)d_in[8];
  const float* w1     = (const float*)d_in[9];
  const float* b1     = (const float*)d_in[10];
  const float* w2     = (const float*)d_in[11];
  const float* b2     = (const float*)d_in[12];

  char* ws = (char*)d_ws;
  unsigned short* qkvT = (unsigned short*)(ws + 0);          // 576*192 bf16
  unsigned short* projT= (unsigned short*)(ws + 221184);     // 192*192
  unsigned short* w1T  = (unsigned short*)(ws + 294912);     // 768*192
  unsigned short* w2T  = (unsigned short*)(ws + 589824);     // 192*768
  unsigned short* bufA = (unsigned short*)(ws + 884736);     // 200704*192 bf16 (xw / attn-out / x2n)
  unsigned short* bufB = (unsigned short*)(ws + 77955072);   // 200704*768 bf16 (qkv / h)
  unsigned short* x2b  = (unsigned short*)(ws + 386236416);  // 200704*192 bf16 (x2)
  float* out = (float*)d_out;
  const int M = 200704;

  wt_kernel<<<432,256,0,stream>>>(qkv_w, qkvT, 192, 576);
  wt_kernel<<<144,256,0,stream>>>(proj_w, projT, 192, 192);
  wt_kernel<<<576,256,0,stream>>>(w1,    w1T,  192, 768);
  wt_kernel<<<576,256,0,stream>>>(w2,    w2T,  768, 192);

  ln_kernel<<<50176,256,0,stream>>>(x, n1_g, n1_b, bufA);
  gemm_k<EPI_QKV  ><<< 9*784, 512,0,stream>>>(bufA, qkvT, qkv_b, nullptr, bufB, M, 576, 9, 192);
  attn_kernel<<<6144,256,0,stream>>>(bufB, bufA);
  gemm_k<EPI_PROJ ><<< 3*784, 512,0,stream>>>(bufA, projT, proj_b, x, x2b, M, 192, 3, 192);
  ln_bf16_kernel<<<50176,256,0,stream>>>(x2b, n2_g, n2_b, bufA);
  gemm_k<EPI_GELU ><<<12*784, 512,0,stream>>>(bufA, w1T, b1, nullptr, bufB, M, 768, 12, 192);
  gemm_k<EPI_FINAL><<< 3*784, 512,0,stream>>>(bufB, w2T, b2, (const float*)x2b, out, M, 192, 3, 768);
}